// Round 1
// baseline (249.588 us; speedup 1.0000x reference)
//
#include <hip/hip_runtime.h>

// Problem dims
#define B_   16
#define C_   256
#define HW_  3136      // 56*56
#define W_   56
#define CR_  128
#define KKG_ 144
#define G_   16
#define D_   16        // C/G
#define NPOS (B_*HW_)  // 50176
#define EPS_ 1e-5f

// ws layout (floats):
//   t    : [B][CR][HW]   = 6,422,528
//   kern : [B][KKG][HW]  = 7,225,344
//   stats: sum[128] | sumsq[128] | scale[128] | shift[128]
#define T_OFF    0
#define KERN_OFF (B_*CR_*HW_)
#define STAT_OFF (KERN_OFF + B_*KKG_*HW_)

__global__ __launch_bounds__(256) void zero_stats(float* stats) {
    stats[threadIdx.x] = 0.0f;   // zeroes sum[128] + sumsq[128]
}

// ---------------------------------------------------------------------------
// K2: t[b,o,p] = sum_c x[b,c,p]*w_reduce[o,c] + b_reduce[o]; accumulate BN sums
// Tile: 64 positions x 128 outputs, K-chunks of 16. Threads: (po 16)x(oc 16),
// each thread: 4 pos x 8 outs.
// ---------------------------------------------------------------------------
__global__ __launch_bounds__(256) void reduce_gemm(
    const float* __restrict__ x, const float* __restrict__ w_reduce,
    const float* __restrict__ b_reduce, float* __restrict__ t,
    float* __restrict__ stats)
{
    __shared__ float xs[16][64];
    __shared__ float wsh[16][128];
    __shared__ float red[128][17];   // +1 pad to break 32-way conflict

    const int tid = threadIdx.x;
    const int po  = tid & 15;
    const int oc  = tid >> 4;
    const int b     = blockIdx.x / 49;
    const int pbase = (blockIdx.x % 49) * 64;

    const float* xb = x + (size_t)b * C_ * HW_ + pbase;

    float acc[4][8];
    #pragma unroll
    for (int j = 0; j < 8; j++) {
        float bias = b_reduce[oc * 8 + j];
        #pragma unroll
        for (int p = 0; p < 4; p++) acc[p][j] = bias;
    }

    for (int c0 = 0; c0 < C_; c0 += 16) {
        // stage x tile: 16 c x 64 p
        #pragma unroll
        for (int i = 0; i < 4; i++) {
            int idx = tid + i * 256;
            int cc = idx >> 6, p = idx & 63;
            xs[cc][p] = xb[(size_t)(c0 + cc) * HW_ + p];
        }
        // stage w tile transposed: wsh[cc][o]
        #pragma unroll
        for (int i = 0; i < 8; i++) {
            int idx = tid + i * 256;
            int o = idx >> 4, cc = idx & 15;
            wsh[cc][o] = w_reduce[o * C_ + c0 + cc];
        }
        __syncthreads();
        #pragma unroll
        for (int cc = 0; cc < 16; cc++) {
            float4 xv = *(const float4*)&xs[cc][po * 4];
            float4 w0 = *(const float4*)&wsh[cc][oc * 8];
            float4 w1 = *(const float4*)&wsh[cc][oc * 8 + 4];
            float xa[4] = {xv.x, xv.y, xv.z, xv.w};
            float wa[8] = {w0.x, w0.y, w0.z, w0.w, w1.x, w1.y, w1.z, w1.w};
            #pragma unroll
            for (int p = 0; p < 4; p++)
                #pragma unroll
                for (int j = 0; j < 8; j++)
                    acc[p][j] = fmaf(xa[p], wa[j], acc[p][j]);
        }
        __syncthreads();
    }

    // write t + per-thread partial BN sums
    float* tb = t + (size_t)b * CR_ * HW_ + pbase;
    float s[8], ss[8];
    #pragma unroll
    for (int j = 0; j < 8; j++) {
        int o = oc * 8 + j;
        float4 v = make_float4(acc[0][j], acc[1][j], acc[2][j], acc[3][j]);
        *(float4*)&tb[(size_t)o * HW_ + po * 4] = v;
        s[j]  = acc[0][j] + acc[1][j] + acc[2][j] + acc[3][j];
        ss[j] = acc[0][j]*acc[0][j] + acc[1][j]*acc[1][j]
              + acc[2][j]*acc[2][j] + acc[3][j]*acc[3][j];
    }
    // block-level channel reduction, then one atomic per channel
    #pragma unroll
    for (int j = 0; j < 8; j++) red[oc * 8 + j][po] = s[j];
    __syncthreads();
    if (tid < 128) {
        float v = 0;
        #pragma unroll
        for (int k = 0; k < 16; k++) v += red[tid][k];
        atomicAdd(&stats[tid], v);
    }
    __syncthreads();
    #pragma unroll
    for (int j = 0; j < 8; j++) red[oc * 8 + j][po] = ss[j];
    __syncthreads();
    if (tid < 128) {
        float v = 0;
        #pragma unroll
        for (int k = 0; k < 16; k++) v += red[tid][k];
        atomicAdd(&stats[128 + tid], v);
    }
}

// ---------------------------------------------------------------------------
// K3: finalize BN: scale = gamma*rsqrt(var+eps), shift = beta - mu*scale
// ---------------------------------------------------------------------------
__global__ __launch_bounds__(128) void finalize_stats(
    float* __restrict__ stats, const float* __restrict__ gamma,
    const float* __restrict__ beta)
{
    int i = threadIdx.x;
    float inv_n = 1.0f / (float)NPOS;
    float mu  = stats[i] * inv_n;
    float var = stats[128 + i] * inv_n - mu * mu;
    float sc  = gamma[i] * rsqrtf(var + EPS_);
    stats[256 + i] = sc;
    stats[384 + i] = beta[i] - mu * sc;
}

// ---------------------------------------------------------------------------
// K4: kern[b,o,p] = sum_cr w_span[o,cr]*relu(t*scale+shift) + b_span[o]
// Tile: 64 pos x 144 outs. Threads: (po 16)x(oc 16), each 4 pos x 9 outs.
// ---------------------------------------------------------------------------
__global__ __launch_bounds__(256) void span_gemm(
    const float* __restrict__ t, const float* __restrict__ w_span,
    const float* __restrict__ b_span, const float* __restrict__ stats,
    float* __restrict__ kern)
{
    __shared__ float ts[16][64];
    __shared__ float wss[16][144];
    __shared__ float scs[128], shs[128];

    const int tid = threadIdx.x;
    const int po  = tid & 15;
    const int oc  = tid >> 4;
    const int b     = blockIdx.x / 49;
    const int pbase = (blockIdx.x % 49) * 64;

    if (tid < 128) { scs[tid] = stats[256 + tid]; shs[tid] = stats[384 + tid]; }

    const float* tb = t + (size_t)b * CR_ * HW_ + pbase;

    float acc[4][9];
    #pragma unroll
    for (int j = 0; j < 9; j++) {
        float bias = b_span[oc * 9 + j];
        #pragma unroll
        for (int p = 0; p < 4; p++) acc[p][j] = bias;
    }
    __syncthreads();   // scs/shs ready

    for (int c0 = 0; c0 < CR_; c0 += 16) {
        #pragma unroll
        for (int i = 0; i < 4; i++) {
            int idx = tid + i * 256;
            int cc = idx >> 6, p = idx & 63;
            int c = c0 + cc;
            float raw = tb[(size_t)c * HW_ + p];
            ts[cc][p] = fmaxf(fmaf(raw, scs[c], shs[c]), 0.0f);
        }
        #pragma unroll
        for (int i = 0; i < 9; i++) {
            int idx = tid + i * 256;
            int o = idx >> 4, cc = idx & 15;
            wss[cc][o] = w_span[o * CR_ + c0 + cc];
        }
        __syncthreads();
        #pragma unroll
        for (int cc = 0; cc < 16; cc++) {
            float4 xv = *(const float4*)&ts[cc][po * 4];
            float xa[4] = {xv.x, xv.y, xv.z, xv.w};
            #pragma unroll
            for (int j = 0; j < 9; j++) {
                float wv = wss[cc][oc * 9 + j];
                #pragma unroll
                for (int p = 0; p < 4; p++)
                    acc[p][j] = fmaf(xa[p], wv, acc[p][j]);
            }
        }
        __syncthreads();
    }

    float* kb = kern + (size_t)b * KKG_ * HW_ + pbase;
    #pragma unroll
    for (int j = 0; j < 9; j++) {
        int o = oc * 9 + j;
        float4 v = make_float4(acc[0][j], acc[1][j], acc[2][j], acc[3][j]);
        *(float4*)&kb[(size_t)o * HW_ + po * 4] = v;
    }
}

// ---------------------------------------------------------------------------
// K5: out[b, g*16+d, p] = sum_{kk} x[b, g*16+d, p+off(kk)] * kern[b, kk*16+g, p]
// One thread per (b,g,pixel); 16 d's per thread (kern loads amortized 16x).
// ---------------------------------------------------------------------------
__global__ __launch_bounds__(256) void involution_apply(
    const float* __restrict__ x, const float* __restrict__ kern,
    float* __restrict__ out)
{
    int gtid = blockIdx.x * 256 + threadIdx.x;
    int pix = gtid % HW_;
    int bg  = gtid / HW_;
    int g = bg & 15;
    int b = bg >> 4;
    int h = pix / W_;
    int w = pix % W_;

    const float* kb = kern + (size_t)b * KKG_ * HW_ + pix;
    float kv[9];
    #pragma unroll
    for (int kk = 0; kk < 9; kk++)
        kv[kk] = kb[(size_t)(kk * G_ + g) * HW_];

    float acc[16];
    #pragma unroll
    for (int d = 0; d < 16; d++) acc[d] = 0.0f;

    const float* xb = x + (size_t)(b * C_ + g * 16) * HW_;
    #pragma unroll
    for (int di = 0; di < 3; di++) {
        int hh = h + di - 1;
        if (hh < 0 || hh >= W_) continue;
        #pragma unroll
        for (int dj = 0; dj < 3; dj++) {
            int ww = w + dj - 1;
            if (ww < 0 || ww >= W_) continue;
            float kval = kv[di * 3 + dj];
            int off = hh * W_ + ww;
            #pragma unroll
            for (int d = 0; d < 16; d++)
                acc[d] = fmaf(xb[(size_t)d * HW_ + off], kval, acc[d]);
        }
    }
    float* ob = out + (size_t)(b * C_ + g * 16) * HW_ + pix;
    #pragma unroll
    for (int d = 0; d < 16; d++) ob[(size_t)d * HW_] = acc[d];
}

extern "C" void kernel_launch(void* const* d_in, const int* in_sizes, int n_in,
                              void* d_out, int out_size, void* d_ws, size_t ws_size,
                              hipStream_t stream) {
    const float* x        = (const float*)d_in[0];
    const float* w_reduce = (const float*)d_in[1];
    const float* b_reduce = (const float*)d_in[2];
    const float* gamma    = (const float*)d_in[3];
    const float* beta     = (const float*)d_in[4];
    const float* w_span   = (const float*)d_in[5];
    const float* b_span   = (const float*)d_in[6];
    float* out = (float*)d_out;

    float* ws    = (float*)d_ws;
    float* t     = ws + T_OFF;
    float* kern  = ws + KERN_OFF;
    float* stats = ws + STAT_OFF;

    zero_stats<<<1, 256, 0, stream>>>(stats);
    reduce_gemm<<<B_ * 49, 256, 0, stream>>>(x, w_reduce, b_reduce, t, stats);
    finalize_stats<<<1, 128, 0, stream>>>(stats, gamma, beta);
    span_gemm<<<B_ * 49, 256, 0, stream>>>(t, w_span, b_span, stats, kern);
    involution_apply<<<(B_ * G_ * HW_) / 256, 256, 0, stream>>>(x, kern, out);
}